// Round 2
// baseline (102.559 us; speedup 1.0000x reference)
//
#include <hip/hip_runtime.h>

#define HID 16
#define R 4
#define TPB 256
#define ROWS_PER_BLOCK (TPB * R)

__device__ __forceinline__ float fast_sigmoid(float x) {
    return __builtin_amdgcn_rcpf(1.0f + __expf(-x));
}
__device__ __forceinline__ float fast_tanh(float x) {
    // 2/(1+e^-2x) - 1; overflow -> inf -> rcp -> 0 -> -1 (correct limit)
    return 2.0f * __builtin_amdgcn_rcpf(1.0f + __expf(-2.0f * x)) - 1.0f;
}

#define DOT16(a, w0, w1, w2, w3, hh) \
    a = fmaf(w0.x, hh[0],  a); a = fmaf(w0.y, hh[1],  a); \
    a = fmaf(w0.z, hh[2],  a); a = fmaf(w0.w, hh[3],  a); \
    a = fmaf(w1.x, hh[4],  a); a = fmaf(w1.y, hh[5],  a); \
    a = fmaf(w1.z, hh[6],  a); a = fmaf(w1.w, hh[7],  a); \
    a = fmaf(w2.x, hh[8],  a); a = fmaf(w2.y, hh[9],  a); \
    a = fmaf(w2.z, hh[10], a); a = fmaf(w2.w, hh[11], a); \
    a = fmaf(w3.x, hh[12], a); a = fmaf(w3.y, hh[13], a); \
    a = fmaf(w3.z, hh[14], a); a = fmaf(w3.w, hh[15], a);

__global__ __launch_bounds__(TPB) void rssm_kernel(
    const float* __restrict__ prev_z,   // [B,3]
    const float* __restrict__ action,   // [B,1]
    const float* __restrict__ prev_h,   // [B,16]
    const float* __restrict__ W_ih,     // [48,4]
    const float* __restrict__ W_hh,     // [48,16]
    const float* __restrict__ b_ih,     // [48]
    const float* __restrict__ b_hh,     // [48]
    const float* __restrict__ W_mu,     // [3,16]
    const float* __restrict__ b_mu,     // [3]
    const float* __restrict__ W_lv,     // [3,16]
    const float* __restrict__ b_lv,     // [3]
    float* __restrict__ out_mu,         // [B,3]
    float* __restrict__ out_lv,         // [B,3]
    float* __restrict__ out_h,          // [B,16]
    int B)
{
    __shared__ float sW_ih[48 * 4];
    __shared__ float sW_hh[48 * HID];
    __shared__ float sbc[48];       // b_ih+b_hh (for r,z gates)
    __shared__ float sbn_i[16];     // b_ih[32+j]
    __shared__ float sbn_h[16];     // b_hh[32+j]
    __shared__ float sHead[16][8];  // per-j: {Wmu0,Wmu1,Wmu2,Wlv0,Wlv1,Wlv2,0,0}
    __shared__ float sb_head[8];    // b_mu[0..2], b_lv[0..2]

    const int t = threadIdx.x;
    if (t < 192) sW_ih[t] = W_ih[t];
    for (int i = t; i < 48 * HID; i += TPB) sW_hh[i] = W_hh[i];
    if (t < 48) sbc[t] = b_ih[t] + b_hh[t];
    if (t < 16) {
        sbn_i[t] = b_ih[32 + t];
        sbn_h[t] = b_hh[32 + t];
        #pragma unroll
        for (int m = 0; m < 3; ++m) {
            sHead[t][m]     = W_mu[m * HID + t];
            sHead[t][3 + m] = W_lv[m * HID + t];
        }
        sHead[t][6] = 0.f; sHead[t][7] = 0.f;
    }
    if (t < 3) { sb_head[t] = b_mu[t]; sb_head[3 + t] = b_lv[t]; }
    __syncthreads();

    const int base = blockIdx.x * ROWS_PER_BLOCK + t;

    // ---- load inputs for R rows (row clamped for safety; B is exact multiple) ----
    int rowv[R];
    float x0[R], x1[R], x2[R], x3[R];
    float h[R][HID];
    #pragma unroll
    for (int r = 0; r < R; ++r) {
        int row = base + r * TPB;
        if (row >= B) row = B - 1;
        rowv[r] = row;
        x0[r] = prev_z[row * 3 + 0];
        x1[r] = prev_z[row * 3 + 1];
        x2[r] = prev_z[row * 3 + 2];
        x3[r] = action[row];
        const float4* hp = (const float4*)(prev_h + (size_t)row * HID);
        #pragma unroll
        for (int q = 0; q < 4; ++q) {
            float4 v = hp[q];
            h[r][q * 4 + 0] = v.x; h[r][q * 4 + 1] = v.y;
            h[r][q * 4 + 2] = v.z; h[r][q * 4 + 3] = v.w;
        }
    }

    float mu0[R], mu1[R], mu2[R], lv0[R], lv1[R], lv2[R];
    #pragma unroll
    for (int r = 0; r < R; ++r) {
        mu0[r] = sb_head[0]; mu1[r] = sb_head[1]; mu2[r] = sb_head[2];
        lv0[r] = sb_head[3]; lv1[r] = sb_head[4]; lv2[r] = sb_head[5];
    }

    #pragma unroll 1
    for (int jo = 0; jo < 4; ++jo) {
        float hn4[R][4];
        #pragma unroll
        for (int ji = 0; ji < 4; ++ji) {
            const int j = jo * 4 + ji;
            float rv[R], zv[R];
            // ---- r gate (row j) ----
            {
                const float4 wi = *(const float4*)&sW_ih[j * 4];
                const float4 w0 = *(const float4*)&sW_hh[j * HID + 0];
                const float4 w1 = *(const float4*)&sW_hh[j * HID + 4];
                const float4 w2 = *(const float4*)&sW_hh[j * HID + 8];
                const float4 w3 = *(const float4*)&sW_hh[j * HID + 12];
                const float b = sbc[j];
                #pragma unroll
                for (int r = 0; r < R; ++r) {
                    float a = b;
                    a = fmaf(wi.x, x0[r], a); a = fmaf(wi.y, x1[r], a);
                    a = fmaf(wi.z, x2[r], a); a = fmaf(wi.w, x3[r], a);
                    DOT16(a, w0, w1, w2, w3, h[r]);
                    rv[r] = fast_sigmoid(a);
                }
            }
            // ---- z gate (row 16+j) ----
            {
                const int g = 16 + j;
                const float4 wi = *(const float4*)&sW_ih[g * 4];
                const float4 w0 = *(const float4*)&sW_hh[g * HID + 0];
                const float4 w1 = *(const float4*)&sW_hh[g * HID + 4];
                const float4 w2 = *(const float4*)&sW_hh[g * HID + 8];
                const float4 w3 = *(const float4*)&sW_hh[g * HID + 12];
                const float b = sbc[g];
                #pragma unroll
                for (int r = 0; r < R; ++r) {
                    float a = b;
                    a = fmaf(wi.x, x0[r], a); a = fmaf(wi.y, x1[r], a);
                    a = fmaf(wi.z, x2[r], a); a = fmaf(wi.w, x3[r], a);
                    DOT16(a, w0, w1, w2, w3, h[r]);
                    zv[r] = fast_sigmoid(a);
                }
            }
            // ---- n gate (row 32+j), new h, fused heads ----
            {
                const int g = 32 + j;
                const float4 wi = *(const float4*)&sW_ih[g * 4];
                const float4 w0 = *(const float4*)&sW_hh[g * HID + 0];
                const float4 w1 = *(const float4*)&sW_hh[g * HID + 4];
                const float4 w2 = *(const float4*)&sW_hh[g * HID + 8];
                const float4 w3 = *(const float4*)&sW_hh[g * HID + 12];
                const float bi = sbn_i[j];
                const float bh = sbn_h[j];
                const float4 hm = *(const float4*)&sHead[j][0]; // mu0,mu1,mu2,lv0
                const float4 hl = *(const float4*)&sHead[j][4]; // lv1,lv2,0,0
                #pragma unroll
                for (int r = 0; r < R; ++r) {
                    float ai = bi;
                    ai = fmaf(wi.x, x0[r], ai); ai = fmaf(wi.y, x1[r], ai);
                    ai = fmaf(wi.z, x2[r], ai); ai = fmaf(wi.w, x3[r], ai);
                    float ah = bh;
                    DOT16(ah, w0, w1, w2, w3, h[r]);
                    const float nv = fast_tanh(fmaf(rv[r], ah, ai));
                    const float hnv = fmaf(zv[r], h[r][j] - nv, nv); // (1-z)*n+z*h
                    hn4[r][ji] = hnv;
                    mu0[r] = fmaf(hm.x, hnv, mu0[r]);
                    mu1[r] = fmaf(hm.y, hnv, mu1[r]);
                    mu2[r] = fmaf(hm.z, hnv, mu2[r]);
                    lv0[r] = fmaf(hm.w, hnv, lv0[r]);
                    lv1[r] = fmaf(hl.x, hnv, lv1[r]);
                    lv2[r] = fmaf(hl.y, hnv, lv2[r]);
                }
            }
        }
        // ---- store this 4-wide chunk of h for each row ----
        #pragma unroll
        for (int r = 0; r < R; ++r) {
            if (base + r * TPB < B)
                *(float4*)(out_h + (size_t)rowv[r] * HID + jo * 4) =
                    make_float4(hn4[r][0], hn4[r][1], hn4[r][2], hn4[r][3]);
        }
    }

    // ---- store mu / logvar ----
    #pragma unroll
    for (int r = 0; r < R; ++r) {
        if (base + r * TPB < B) {
            const int row = rowv[r];
            out_mu[row * 3 + 0] = mu0[r];
            out_mu[row * 3 + 1] = mu1[r];
            out_mu[row * 3 + 2] = mu2[r];
            out_lv[row * 3 + 0] = fminf(fmaxf(lv0[r], -5.0f), 5.0f);
            out_lv[row * 3 + 1] = fminf(fmaxf(lv1[r], -5.0f), 5.0f);
            out_lv[row * 3 + 2] = fminf(fmaxf(lv2[r], -5.0f), 5.0f);
        }
    }
}

extern "C" void kernel_launch(void* const* d_in, const int* in_sizes, int n_in,
                              void* d_out, int out_size, void* d_ws, size_t ws_size,
                              hipStream_t stream) {
    const float* prev_z = (const float*)d_in[0];
    const float* action = (const float*)d_in[1];
    const float* prev_h = (const float*)d_in[2];
    const float* W_ih   = (const float*)d_in[3];
    const float* W_hh   = (const float*)d_in[4];
    const float* b_ih   = (const float*)d_in[5];
    const float* b_hh   = (const float*)d_in[6];
    const float* W_mu   = (const float*)d_in[7];
    const float* b_mu   = (const float*)d_in[8];
    const float* W_lv   = (const float*)d_in[9];
    const float* b_lv   = (const float*)d_in[10];

    const int B = in_sizes[0] / 3;
    float* out    = (float*)d_out;
    float* out_mu = out;
    float* out_lv = out + (size_t)3 * B;
    float* out_h  = out + (size_t)6 * B;

    const int blocks = (B + ROWS_PER_BLOCK - 1) / ROWS_PER_BLOCK;
    rssm_kernel<<<blocks, TPB, 0, stream>>>(prev_z, action, prev_h,
                                            W_ih, W_hh, b_ih, b_hh,
                                            W_mu, b_mu, W_lv, b_lv,
                                            out_mu, out_lv, out_h, B);
}

// Round 3
// 59.607 us; speedup vs baseline: 1.7206x; 1.7206x over previous
//
#include <hip/hip_runtime.h>

#define HID 16
#define TPB 256

__device__ __forceinline__ float fast_sigmoid(float x) {
    return __builtin_amdgcn_rcpf(1.0f + __expf(-x));
}
__device__ __forceinline__ float fast_tanh(float x) {
    // 2/(1+e^-2x) - 1; overflow -> inf -> rcp -> 0 -> -1 (correct limit)
    return 2.0f * __builtin_amdgcn_rcpf(1.0f + __expf(-2.0f * x)) - 1.0f;
}

// dot of uniform weight row (scalar-loaded) with per-lane h[16]
#define DOT16(a, w0, w1, w2, w3, hh) \
    a = fmaf(w0.x, hh[0],  a); a = fmaf(w0.y, hh[1],  a); \
    a = fmaf(w0.z, hh[2],  a); a = fmaf(w0.w, hh[3],  a); \
    a = fmaf(w1.x, hh[4],  a); a = fmaf(w1.y, hh[5],  a); \
    a = fmaf(w1.z, hh[6],  a); a = fmaf(w1.w, hh[7],  a); \
    a = fmaf(w2.x, hh[8],  a); a = fmaf(w2.y, hh[9],  a); \
    a = fmaf(w2.z, hh[10], a); a = fmaf(w2.w, hh[11], a); \
    a = fmaf(w3.x, hh[12], a); a = fmaf(w3.y, hh[13], a); \
    a = fmaf(w3.z, hh[14], a); a = fmaf(w3.w, hh[15], a);

__global__ __launch_bounds__(TPB) void rssm_kernel(
    const float* __restrict__ prev_z,   // [B,3]
    const float* __restrict__ action,   // [B,1]
    const float* __restrict__ prev_h,   // [B,16]
    const float* __restrict__ W_ih,     // [48,4]
    const float* __restrict__ W_hh,     // [48,16]
    const float* __restrict__ b_ih,     // [48]
    const float* __restrict__ b_hh,     // [48]
    const float* __restrict__ W_mu,     // [3,16]
    const float* __restrict__ b_mu,     // [3]
    const float* __restrict__ W_lv,     // [3,16]
    const float* __restrict__ b_lv,     // [3]
    float* __restrict__ out_mu,         // [B,3]
    float* __restrict__ out_lv,         // [B,3]
    float* __restrict__ out_h,          // [B,16]
    int B)
{
    const int row = blockIdx.x * TPB + threadIdx.x;
    if (row >= B) return;

    // ---- per-lane inputs ----
    const float x0 = prev_z[row * 3 + 0];
    const float x1 = prev_z[row * 3 + 1];
    const float x2 = prev_z[row * 3 + 2];
    const float x3 = action[row];

    float h[HID];
    {
        const float4* hp = (const float4*)(prev_h + (size_t)row * HID);
        #pragma unroll
        for (int q = 0; q < 4; ++q) {
            float4 v = hp[q];
            h[q*4+0] = v.x; h[q*4+1] = v.y; h[q*4+2] = v.z; h[q*4+3] = v.w;
        }
    }

    float hn[HID];

    // ---- GRU gates; all weight reads are wave-uniform -> s_load (SMEM pipe) ----
    #pragma unroll 2
    for (int j = 0; j < HID; ++j) {
        float rv, zv;
        // r gate (row j)
        {
            const float4 wi = *(const float4*)&W_ih[j * 4];
            const float4 w0 = *(const float4*)&W_hh[j * HID + 0];
            const float4 w1 = *(const float4*)&W_hh[j * HID + 4];
            const float4 w2 = *(const float4*)&W_hh[j * HID + 8];
            const float4 w3 = *(const float4*)&W_hh[j * HID + 12];
            float a = b_ih[j] + b_hh[j];
            a = fmaf(wi.x, x0, a); a = fmaf(wi.y, x1, a);
            a = fmaf(wi.z, x2, a); a = fmaf(wi.w, x3, a);
            DOT16(a, w0, w1, w2, w3, h);
            rv = fast_sigmoid(a);
        }
        // z gate (row 16+j)
        {
            const int g = HID + j;
            const float4 wi = *(const float4*)&W_ih[g * 4];
            const float4 w0 = *(const float4*)&W_hh[g * HID + 0];
            const float4 w1 = *(const float4*)&W_hh[g * HID + 4];
            const float4 w2 = *(const float4*)&W_hh[g * HID + 8];
            const float4 w3 = *(const float4*)&W_hh[g * HID + 12];
            float a = b_ih[g] + b_hh[g];
            a = fmaf(wi.x, x0, a); a = fmaf(wi.y, x1, a);
            a = fmaf(wi.z, x2, a); a = fmaf(wi.w, x3, a);
            DOT16(a, w0, w1, w2, w3, h);
            zv = fast_sigmoid(a);
        }
        // n gate (row 32+j) + h update
        {
            const int g = 2 * HID + j;
            const float4 wi = *(const float4*)&W_ih[g * 4];
            const float4 w0 = *(const float4*)&W_hh[g * HID + 0];
            const float4 w1 = *(const float4*)&W_hh[g * HID + 4];
            const float4 w2 = *(const float4*)&W_hh[g * HID + 8];
            const float4 w3 = *(const float4*)&W_hh[g * HID + 12];
            float ai = b_ih[g];
            ai = fmaf(wi.x, x0, ai); ai = fmaf(wi.y, x1, ai);
            ai = fmaf(wi.z, x2, ai); ai = fmaf(wi.w, x3, ai);
            float ah = b_hh[g];
            DOT16(ah, w0, w1, w2, w3, h);
            const float nv = fast_tanh(fmaf(rv, ah, ai));
            hn[j] = fmaf(zv, h[j] - nv, nv);   // (1-z)*n + z*h
        }
    }

    // ---- heads (weights uniform -> s_load) ----
    float m0 = b_mu[0], m1 = b_mu[1], m2 = b_mu[2];
    float l0 = b_lv[0], l1 = b_lv[1], l2 = b_lv[2];
    #pragma unroll
    for (int k = 0; k < HID; k += 4) {
        const float4 wm0 = *(const float4*)&W_mu[0 * HID + k];
        const float4 wm1 = *(const float4*)&W_mu[1 * HID + k];
        const float4 wm2 = *(const float4*)&W_mu[2 * HID + k];
        const float4 wl0 = *(const float4*)&W_lv[0 * HID + k];
        const float4 wl1 = *(const float4*)&W_lv[1 * HID + k];
        const float4 wl2 = *(const float4*)&W_lv[2 * HID + k];
        m0 = fmaf(wm0.x, hn[k], m0); m0 = fmaf(wm0.y, hn[k+1], m0);
        m0 = fmaf(wm0.z, hn[k+2], m0); m0 = fmaf(wm0.w, hn[k+3], m0);
        m1 = fmaf(wm1.x, hn[k], m1); m1 = fmaf(wm1.y, hn[k+1], m1);
        m1 = fmaf(wm1.z, hn[k+2], m1); m1 = fmaf(wm1.w, hn[k+3], m1);
        m2 = fmaf(wm2.x, hn[k], m2); m2 = fmaf(wm2.y, hn[k+1], m2);
        m2 = fmaf(wm2.z, hn[k+2], m2); m2 = fmaf(wm2.w, hn[k+3], m2);
        l0 = fmaf(wl0.x, hn[k], l0); l0 = fmaf(wl0.y, hn[k+1], l0);
        l0 = fmaf(wl0.z, hn[k+2], l0); l0 = fmaf(wl0.w, hn[k+3], l0);
        l1 = fmaf(wl1.x, hn[k], l1); l1 = fmaf(wl1.y, hn[k+1], l1);
        l1 = fmaf(wl1.z, hn[k+2], l1); l1 = fmaf(wl1.w, hn[k+3], l1);
        l2 = fmaf(wl2.x, hn[k], l2); l2 = fmaf(wl2.y, hn[k+1], l2);
        l2 = fmaf(wl2.z, hn[k+2], l2); l2 = fmaf(wl2.w, hn[k+3], l2);
    }

    // ---- stores: full 64B h row back-to-back (write-merging, per R1 evidence) ----
    float4* ho = (float4*)(out_h + (size_t)row * HID);
    ho[0] = make_float4(hn[0],  hn[1],  hn[2],  hn[3]);
    ho[1] = make_float4(hn[4],  hn[5],  hn[6],  hn[7]);
    ho[2] = make_float4(hn[8],  hn[9],  hn[10], hn[11]);
    ho[3] = make_float4(hn[12], hn[13], hn[14], hn[15]);

    out_mu[row * 3 + 0] = m0;
    out_mu[row * 3 + 1] = m1;
    out_mu[row * 3 + 2] = m2;
    out_lv[row * 3 + 0] = fminf(fmaxf(l0, -5.0f), 5.0f);
    out_lv[row * 3 + 1] = fminf(fmaxf(l1, -5.0f), 5.0f);
    out_lv[row * 3 + 2] = fminf(fmaxf(l2, -5.0f), 5.0f);
}

extern "C" void kernel_launch(void* const* d_in, const int* in_sizes, int n_in,
                              void* d_out, int out_size, void* d_ws, size_t ws_size,
                              hipStream_t stream) {
    const float* prev_z = (const float*)d_in[0];
    const float* action = (const float*)d_in[1];
    const float* prev_h = (const float*)d_in[2];
    const float* W_ih   = (const float*)d_in[3];
    const float* W_hh   = (const float*)d_in[4];
    const float* b_ih   = (const float*)d_in[5];
    const float* b_hh   = (const float*)d_in[6];
    const float* W_mu   = (const float*)d_in[7];
    const float* b_mu   = (const float*)d_in[8];
    const float* W_lv   = (const float*)d_in[9];
    const float* b_lv   = (const float*)d_in[10];

    const int B = in_sizes[0] / 3;
    float* out    = (float*)d_out;
    float* out_mu = out;
    float* out_lv = out + (size_t)3 * B;
    float* out_h  = out + (size_t)6 * B;

    const int blocks = (B + TPB - 1) / TPB;
    rssm_kernel<<<blocks, TPB, 0, stream>>>(prev_z, action, prev_h,
                                            W_ih, W_hh, b_ih, b_hh,
                                            W_mu, b_mu, W_lv, b_lv,
                                            out_mu, out_lv, out_h, B);
}